// Round 1
// baseline (910.431 us; speedup 1.0000x reference)
//
#include <hip/hip_runtime.h>
#include <math.h>

#define NBATCH 8
#define TLEN   4096
#define DDIM   1024
#define NLAY   8
#define NDM    16
#define OUTD   384
#define NTOK   (NBATCH*TLEN)
#define TPW    32            // tokens per workgroup
#define KT     32            // K chunk
#define KTP    36            // padded LDS row for A (bank-conflict-free reads)
#define POUT   385           // padded LDS row for params (tok-stride -> bank+1)
#define DELTA_F 1e-6f

__device__ __forceinline__ float softplusf(float v){
    return fmaxf(v, 0.f) + log1pf(expf(-fabsf(v)));
}

__global__ void init_out_kernel(const float* __restrict__ logdet_in, float* __restrict__ out){
    int i = (int)threadIdx.x;
    if (i < NBATCH) out[2*NTOK + i] = logdet_in[i];
}

__global__ void __launch_bounds__(256, 2)
fused_sigmoidal(const float* __restrict__ x,
                const float* __restrict__ cond_o,
                const float* __restrict__ mask,
                const float* __restrict__ W,
                const float* __restrict__ bias,
                float* __restrict__ out)
{
    __shared__ __align__(16) float A[TPW][KTP];   // cond_o K-chunk
    __shared__ float P[TPW][POUT];                // all 384 params per token

    const int tid  = (int)threadIdx.x;
    const int tok0 = (int)blockIdx.x * TPW;
    const int tg   = tid & 3;    // token group (4)
    const int og   = tid >> 2;   // output group (64), 6 outputs each

    float acc[8][6];
    #pragma unroll
    for (int j=0;j<8;++j){
        #pragma unroll
        for (int o=0;o<6;++o) acc[j][o] = 0.f;
    }

    // staging decomposition: 32 rows x 8 quads
    const int srow = tid >> 3;
    const int sq   = tid & 7;
    const float* srcA = cond_o + (size_t)(tok0 + srow)*DDIM + sq*4;

    float4 st = *(const float4*)srcA;   // prefetch chunk 0

    for (int c=0; c<DDIM/KT; ++c){
        __syncthreads();
        *(float4*)&A[srow][sq*4] = st;
        __syncthreads();
        if (c+1 < DDIM/KT) st = *(const float4*)(srcA + (c+1)*KT);
        const int kb = c*KT;
        #pragma unroll 2
        for (int kq=0; kq<KT/4; ++kq){
            float4 av[8];
            #pragma unroll
            for (int j=0;j<8;++j) av[j] = *(const float4*)&A[tg + 4*j][kq*4];
            float4 wv[6];
            #pragma unroll
            for (int o=0;o<6;++o)
                wv[o] = *(const float4*)&W[(size_t)(og*6+o)*DDIM + kb + kq*4];
            #pragma unroll
            for (int j=0;j<8;++j){
                #pragma unroll
                for (int o=0;o<6;++o){
                    acc[j][o] = fmaf(av[j].x, wv[o].x, acc[j][o]);
                    acc[j][o] = fmaf(av[j].y, wv[o].y, acc[j][o]);
                    acc[j][o] = fmaf(av[j].z, wv[o].z, acc[j][o]);
                    acc[j][o] = fmaf(av[j].w, wv[o].w, acc[j][o]);
                }
            }
        }
    }

    // write params (+bias, *mask) to LDS
    #pragma unroll
    for (int j=0;j<8;++j){
        const int row = tg + 4*j;
        const float mk = mask[tok0+row];
        #pragma unroll
        for (int o=0;o<6;++o){
            const int oo = og*6 + o;
            P[row][oo] = (acc[j][o] + bias[oo]) * mk;
        }
    }
    __syncthreads();

    // epilogue: one lane per token (lanes 0..31 of wave 0)
    if (tid < TPW){
        const int gt = tok0 + tid;
        const float mk = mask[gt];
        float z = x[gt]*mk;
        float ld_acc = 0.f;
        const float LOG1MD = -1.0000005e-06f;   // log(1-1e-6)
        #pragma unroll 1
        for (int l=0;l<NLAY;++l){
            const int bp = l*48;
            float pa[16], pb[16], pw[16];
            #pragma unroll
            for (int i=0;i<16;++i){
                pa[i] = P[tid][bp+i];
                pb[i] = P[tid][bp+16+i];
                pw[i] = P[tid][bp+32+i];
            }
            float m = pw[0];
            #pragma unroll
            for (int i=1;i<16;++i) m = fmaxf(m, pw[i]);
            float aa[16], pre[16];
            float s = 0.f, xp = 0.f;
            #pragma unroll
            for (int i=0;i<16;++i){
                float e = expf(pw[i]-m);
                s += e;
                aa[i]  = softplusf(pa[i]);
                pre[i] = fmaf(aa[i], z, pb[i]);
                float t = expf(-fabsf(pre[i]));
                float r = 1.f/(1.f+t);
                float sg = (pre[i] >= 0.f) ? r : t*r;
                xp = fmaf(e, sg, xp);
            }
            float x_pre = xp/s;
            float xpc = fmaf(x_pre, 1.f-DELTA_F, 0.5f*DELTA_F);
            float lx = logf(xpc);
            float l1 = log1pf(-xpc);
            float logs = logf(s);
            float lj[16];
            float M = -3.0e38f;
            #pragma unroll
            for (int i=0;i<16;++i){
                float ap = fabsf(pre[i]);
                float spsum = ap + 2.f*log1pf(expf(-ap));   // sp(pre)+sp(-pre)
                lj[i] = (pw[i]-m-logs) - spsum + logf(aa[i]);
                M = fmaxf(M, lj[i]);
            }
            float S = 0.f;
            #pragma unroll
            for (int i=0;i<16;++i) S += expf(lj[i]-M);
            float logj = M + logf(S);
            float ld_ = logj + LOG1MD - lx - l1;
            ld_acc = fmaf(ld_, mk, ld_acc);
            z = lx - l1;
        }
        out[gt]       = z;
        out[NTOK+gt]  = mk;
        // reduce logdet across the 32 lanes (all same batch: 4096 % 32 == 0)
        #pragma unroll
        for (int off=16; off>=1; off>>=1)
            ld_acc += __shfl_xor(ld_acc, off, 32);
        if (tid == 0) atomicAdd(&out[2*NTOK + (gt >> 12)], ld_acc);
    }
}

extern "C" void kernel_launch(void* const* d_in, const int* in_sizes, int n_in,
                              void* d_out, int out_size, void* d_ws, size_t ws_size,
                              hipStream_t stream)
{
    const float* x      = (const float*)d_in[0];
    const float* cond_o = (const float*)d_in[1];
    const float* mask   = (const float*)d_in[2];
    const float* logdet = (const float*)d_in[3];
    const float* W      = (const float*)d_in[4];
    const float* bias   = (const float*)d_in[5];
    float* out = (float*)d_out;

    hipLaunchKernelGGL(init_out_kernel, dim3(1), dim3(64), 0, stream, logdet, out);
    hipLaunchKernelGGL(fused_sigmoidal, dim3(NTOK/TPW), dim3(256), 0, stream,
                       x, cond_o, mask, W, bias, out);
}